// Round 2
// baseline (806.806 us; speedup 1.0000x reference)
//
#include <hip/hip_runtime.h>
#include <cstdint>

#define BB 8
#define CC 256
#define HH 128
#define WW 128
#define HW (HH * WW)

// ---------------------------------------------------------------------------
// Kernel A: per-position channel mean & max of x -> y (B, 2, H, W) in d_ws
// One block per (b, h) row. 256 threads: 8 channel-groups x 32 float4 lanes.
// ---------------------------------------------------------------------------
__global__ __launch_bounds__(256) void reduce_meanmax(const float* __restrict__ x,
                                                      float* __restrict__ y) {
    const int bh = blockIdx.x;
    const int b  = bh >> 7;      // / HH
    const int h  = bh & 127;     // % HH
    const int t  = threadIdx.x;
    const int wq = t & 31;       // float4 column: w = wq*4
    const int cg = t >> 5;       // channel group 0..7 (32 channels each)

    const float* xb = x + ((size_t)(b * CC + cg * 32) * HH + h) * WW;

    float4 s = make_float4(0.f, 0.f, 0.f, 0.f);
    float4 m = make_float4(-INFINITY, -INFINITY, -INFINITY, -INFINITY);
    #pragma unroll 4
    for (int i = 0; i < 32; ++i) {
        float4 v = ((const float4*)(xb + (size_t)i * HW))[wq];
        s.x += v.x; s.y += v.y; s.z += v.z; s.w += v.w;
        m.x = fmaxf(m.x, v.x); m.y = fmaxf(m.y, v.y);
        m.z = fmaxf(m.z, v.z); m.w = fmaxf(m.w, v.w);
    }

    __shared__ float4 ls[8][32];
    __shared__ float4 lm[8][32];
    ls[cg][wq] = s;
    lm[cg][wq] = m;
    __syncthreads();

    if (t < 32) {
        float4 S = ls[0][t];
        float4 M = lm[0][t];
        #pragma unroll
        for (int g = 1; g < 8; ++g) {
            float4 a = ls[g][t];
            float4 c = lm[g][t];
            S.x += a.x; S.y += a.y; S.z += a.z; S.w += a.w;
            M.x = fmaxf(M.x, c.x); M.y = fmaxf(M.y, c.y);
            M.z = fmaxf(M.z, c.z); M.w = fmaxf(M.w, c.w);
        }
        const float inv = 1.0f / 256.0f;
        float4 mean = make_float4(S.x * inv, S.y * inv, S.z * inv, S.w * inv);
        float4* ym = (float4*)(y + ((size_t)(b * 2 + 0)) * HW + h * WW);
        float4* yx = (float4*)(y + ((size_t)(b * 2 + 1)) * HW + h * WW);
        ym[t] = mean;
        yx[t] = M;
    }
}

// ---------------------------------------------------------------------------
// Kernel B: fused 7x7 offset-conv + deformable bilinear sampling + BN+sigmoid
// gate, broadcast-written to out (B, C, H, W).
// One thread per spatial position. Conv restructured as 7 groups (one per
// kernel row) of 21 independent accumulators (7 taps x {dy,dx,mask}) so the
// VALU has ILP ~21 instead of 3.
// ---------------------------------------------------------------------------
__global__ __launch_bounds__(128) void deform_att(
    const float* __restrict__ y,
    const float* __restrict__ w_off, const float* __restrict__ b_off,
    const float* __restrict__ w_dcn, const float* __restrict__ b_dcn,
    const float* __restrict__ bn_gamma, const float* __restrict__ bn_beta,
    const float* __restrict__ bn_mean, const float* __restrict__ bn_var,
    float* __restrict__ out)
{
    const int bh = blockIdx.x;
    const int b  = bh >> 7;
    const int h  = bh & 127;
    const int t  = threadIdx.x;
    const int w  = t;

    // ---- stage the zero-padded 2x7x(128+6) patch rows into LDS ----
    __shared__ float patch[2][7][136];   // [ci][row][x+3], x in [-3, 132]
    for (int i = t; i < 2 * 7 * 136; i += 128) {
        const int ci  = i / (7 * 136);
        const int rem = i % (7 * 136);
        const int r   = rem / 136;
        const int xi  = rem % 136;       // padded x index
        const int xx  = xi - 3;
        const int yy  = h + r - 3;
        float v = 0.0f;
        if (yy >= 0 && yy < HH && xx >= 0 && xx < WW)
            v = y[((size_t)(b * 2 + ci)) * HW + yy * WW + xx];
        patch[ci][r][xi] = v;
    }
    __syncthreads();

    // ---- pull this thread's 98-value conv patch into registers ----
    float p[98];
    #pragma unroll
    for (int ci = 0; ci < 2; ++ci)
        #pragma unroll
        for (int r = 0; r < 7; ++r)
            #pragma unroll
            for (int c = 0; c < 7; ++c)
                p[ci * 49 + r * 7 + c] = patch[ci][r][w + c];

    const float* ym = y + (size_t)(b * 2) * HW;      // mean plane
    const float* yx = ym + HW;                       // max plane
    const float bn_scale = bn_gamma[0] * rsqrtf(bn_var[0] + 1e-5f);

    float out_acc = 0.0f;

    #pragma unroll 1
    for (int kr = 0; kr < 7; ++kr) {
        // conv channels for this kernel row: dy/dx = [14kr, 14kr+14), mask = [98+7kr, 98+7kr+7)
        const float* wb = w_off + (size_t)(14 * kr) * 98;
        const float* mb = w_off + (size_t)(98 + 7 * kr) * 98;

        float accY[7], accX[7], accM[7];
        #pragma unroll
        for (int kc = 0; kc < 7; ++kc) {
            accY[kc] = b_off[14 * kr + 2 * kc];
            accX[kc] = b_off[14 * kr + 2 * kc + 1];
            accM[kc] = b_off[98 + 7 * kr + kc];
        }

        #pragma unroll
        for (int j = 0; j < 98; ++j) {
            const float pj = p[j];
            #pragma unroll
            for (int kc = 0; kc < 7; ++kc) {
                accY[kc] = fmaf(wb[(size_t)(2 * kc) * 98 + j],     pj, accY[kc]);
                accX[kc] = fmaf(wb[(size_t)(2 * kc + 1) * 98 + j], pj, accX[kc]);
                accM[kc] = fmaf(mb[(size_t)kc * 98 + j],           pj, accM[kc]);
            }
        }

        // ---- bilinear sampling for the 7 taps of this kernel row ----
        #pragma unroll
        for (int kc = 0; kc < 7; ++kc) {
            const int k = kr * 7 + kc;
            const float mk = 1.0f / (1.0f + __expf(-accM[kc]));

            const float fy = (float)(h + kr - 3) + accY[kc];
            const float fx = (float)(w + kc - 3) + accX[kc];
            const float fly = floorf(fy), flx = floorf(fx);
            const int iy0 = (int)fly, ix0 = (int)flx;
            const int iy1 = iy0 + 1,  ix1 = ix0 + 1;
            const float wy1 = fy - fly, wy0 = 1.0f - wy1;
            const float wx1 = fx - flx, wx0 = 1.0f - wx1;

            const float vy0 = (iy0 >= 0 && iy0 < HH) ? 1.0f : 0.0f;
            const float vy1 = (iy1 >= 0 && iy1 < HH) ? 1.0f : 0.0f;
            const float vx0 = (ix0 >= 0 && ix0 < WW) ? 1.0f : 0.0f;
            const float vx1 = (ix1 >= 0 && ix1 < WW) ? 1.0f : 0.0f;

            const int cy0 = min(max(iy0, 0), HH - 1) * WW;
            const int cy1 = min(max(iy1, 0), HH - 1) * WW;
            const int cx0 = min(max(ix0, 0), WW - 1);
            const int cx1 = min(max(ix1, 0), WW - 1);

            const float w00 = wy0 * wx0 * vy0 * vx0;
            const float w01 = wy0 * wx1 * vy0 * vx1;
            const float w10 = wy1 * wx0 * vy1 * vx0;
            const float w11 = wy1 * wx1 * vy1 * vx1;

            const int i00 = cy0 + cx0, i01 = cy0 + cx1;
            const int i10 = cy1 + cx0, i11 = cy1 + cx1;

            const float v0 = ym[i00] * w00 + ym[i01] * w01 + ym[i10] * w10 + ym[i11] * w11;
            const float v1 = yx[i00] * w00 + yx[i01] * w01 + yx[i10] * w10 + yx[i11] * w11;

            out_acc = fmaf(mk, fmaf(v0, w_dcn[k], v1 * w_dcn[49 + k]), out_acc);
        }
    }

    float o = out_acc + b_dcn[0];
    o = (o - bn_mean[0]) * bn_scale + bn_beta[0];
    const float gate = 1.0f / (1.0f + __expf(-o));

    // ---- broadcast write across all 256 channels (coalesced in w) ----
    float* op = out + (size_t)(b * CC) * HW + h * WW + w;
    #pragma unroll 8
    for (int c = 0; c < CC; ++c) {
        op[(size_t)c * HW] = gate;
    }
}

extern "C" void kernel_launch(void* const* d_in, const int* in_sizes, int n_in,
                              void* d_out, int out_size, void* d_ws, size_t ws_size,
                              hipStream_t stream) {
    const float* x        = (const float*)d_in[0];
    const float* w_off    = (const float*)d_in[1];
    const float* b_off    = (const float*)d_in[2];
    const float* w_dcn    = (const float*)d_in[3];
    const float* b_dcn    = (const float*)d_in[4];
    const float* bn_gamma = (const float*)d_in[5];
    const float* bn_beta  = (const float*)d_in[6];
    const float* bn_mean  = (const float*)d_in[7];
    const float* bn_var   = (const float*)d_in[8];
    float* out = (float*)d_out;

    float* y = (float*)d_ws;   // (B, 2, H, W) = 1 MiB

    reduce_meanmax<<<BB * HH, 256, 0, stream>>>(x, y);
    deform_att<<<BB * HH, 128, 0, stream>>>(y, w_off, b_off, w_dcn, b_dcn,
                                            bn_gamma, bn_beta, bn_mean, bn_var,
                                            out);
}

// Round 3
// 788.936 us; speedup vs baseline: 1.0227x; 1.0227x over previous
//
#include <hip/hip_runtime.h>
#include <cstdint>

#define BB 8
#define CC 256
#define HH 128
#define WW 128
#define HW (HH * WW)

// ---------------------------------------------------------------------------
// Kernel A: per-position channel mean & max of x -> y2 (B, H*W, 2) float2
// interleaved {mean, max}. One block per (b, h) row; 512 threads =
// 16 channel-groups x 32 float4 lanes.
// ---------------------------------------------------------------------------
__global__ __launch_bounds__(512) void reduce_meanmax(const float* __restrict__ x,
                                                      float* __restrict__ y2) {
    const int bh = blockIdx.x;
    const int b  = bh >> 7;
    const int h  = bh & 127;
    const int t  = threadIdx.x;
    const int wq = t & 31;       // float4 column: w = wq*4
    const int cg = t >> 5;       // channel group 0..15 (16 channels each)

    const float* xb = x + ((size_t)(b * CC + cg * 16) * HH + h) * WW;

    float4 s = make_float4(0.f, 0.f, 0.f, 0.f);
    float4 m = make_float4(-INFINITY, -INFINITY, -INFINITY, -INFINITY);
    #pragma unroll 4
    for (int i = 0; i < 16; ++i) {
        float4 v = ((const float4*)(xb + (size_t)i * HW))[wq];
        s.x += v.x; s.y += v.y; s.z += v.z; s.w += v.w;
        m.x = fmaxf(m.x, v.x); m.y = fmaxf(m.y, v.y);
        m.z = fmaxf(m.z, v.z); m.w = fmaxf(m.w, v.w);
    }

    __shared__ float4 ls[16][32];
    __shared__ float4 lm[16][32];
    ls[cg][wq] = s;
    lm[cg][wq] = m;
    __syncthreads();

    if (t < 32) {
        float4 S = ls[0][t];
        float4 M = lm[0][t];
        #pragma unroll
        for (int g = 1; g < 16; ++g) {
            float4 a = ls[g][t];
            float4 c = lm[g][t];
            S.x += a.x; S.y += a.y; S.z += a.z; S.w += a.w;
            M.x = fmaxf(M.x, c.x); M.y = fmaxf(M.y, c.y);
            M.z = fmaxf(M.z, c.z); M.w = fmaxf(M.w, c.w);
        }
        const float inv = 1.0f / 256.0f;
        // interleaved {mean, max} pairs, two float4 per thread (4 positions)
        float4 o0 = make_float4(S.x * inv, M.x, S.y * inv, M.y);
        float4 o1 = make_float4(S.z * inv, M.z, S.w * inv, M.w);
        float4* yo = (float4*)(y2 + ((size_t)b * HW + (size_t)h * WW) * 2);
        yo[2 * t]     = o0;
        yo[2 * t + 1] = o1;
    }
}

// ---------------------------------------------------------------------------
// Kernel B: channel-per-lane conv + deformable sampling + gate broadcast.
// Block = 192 threads (3 waves). Wave 0 = dy channels, wave 1 = dx,
// wave 2 = mask; lane l < 49 = tap k. Weights live in 98 VGPRs per lane,
// loaded ONCE. Patch values are wave-uniform LDS broadcasts.
// Positions processed in chunks of 6; sampling: wave wv owns positions
// {wv, wv+3} of the chunk, lane = tap, shfl-reduce over taps.
// ---------------------------------------------------------------------------
__global__ __launch_bounds__(192, 3) void deform_att(
    const float* __restrict__ y2,
    const float* __restrict__ w_off, const float* __restrict__ b_off,
    const float* __restrict__ w_dcn, const float* __restrict__ b_dcn,
    const float* __restrict__ bn_gamma, const float* __restrict__ bn_beta,
    const float* __restrict__ bn_mean, const float* __restrict__ bn_var,
    float* __restrict__ out)
{
    const int bh = blockIdx.x;
    const int b  = bh >> 7;
    const int h  = bh & 127;
    const int t  = threadIdx.x;
    const int wv = t >> 6;          // 0: dy, 1: dx, 2: mask
    const int l  = t & 63;
    const bool act = (l < 49);
    const int ls = act ? l : 0;     // clamped tap index

    __shared__ float patch[2][7][140];   // zero-padded row window
    __shared__ float cv[3][6][52];       // conv outputs: [type][pos-in-chunk][tap]
    __shared__ float gate_row[128];

    const float2* y2b = (const float2*)y2 + (size_t)b * HW;

    // ---- stage the zero-padded 2x7x140 patch window into LDS ----
    for (int i = t; i < 7 * 140; i += 192) {
        const int r  = i / 140;
        const int xi = i % 140;
        const int xx = xi - 3;
        const int yy = h + r - 3;
        float2 v = make_float2(0.f, 0.f);
        if (yy >= 0 && yy < HH && xx >= 0 && xx < WW)
            v = y2b[yy * WW + xx];
        patch[0][r][xi] = v.x;
        patch[1][r][xi] = v.y;
    }

    // ---- per-lane channel weights, loaded once into registers ----
    const int ch = (wv == 0) ? 2 * ls : (wv == 1) ? (2 * ls + 1) : (98 + ls);
    float w_reg[98];
    {
        const float2* wp = (const float2*)(w_off + ch * 98);
        #pragma unroll
        for (int q = 0; q < 49; ++q) {
            float2 t2 = wp[q];
            w_reg[2 * q]     = t2.x;
            w_reg[2 * q + 1] = t2.y;
        }
    }
    const float b_reg = b_off[ch];
    const float wd0 = w_dcn[ls];
    const float wd1 = w_dcn[49 + ls];
    const int kr = ls / 7;
    const int kc = ls % 7;
    const float bscale = bn_gamma[0] * rsqrtf(bn_var[0] + 1e-5f);
    const float gB = (b_dcn[0] - bn_mean[0]) * bscale + bn_beta[0];

    __syncthreads();

    #pragma unroll 1
    for (int chunk = 0; chunk < 22; ++chunk) {
        const int base = chunk * 6;

        // ---- conv: this lane's channel for 6 positions ----
        float acc[6];
        #pragma unroll
        for (int pp = 0; pp < 6; ++pp) acc[pp] = b_reg;

        #pragma unroll
        for (int ci = 0; ci < 2; ++ci) {
            #pragma unroll
            for (int r = 0; r < 7; ++r) {
                float v[12];
                #pragma unroll
                for (int q = 0; q < 6; ++q) {
                    float2 t2 = *(const float2*)&patch[ci][r][base + 2 * q];
                    v[2 * q]     = t2.x;
                    v[2 * q + 1] = t2.y;
                }
                #pragma unroll
                for (int c = 0; c < 7; ++c) {
                    const float wj = w_reg[ci * 49 + r * 7 + c];
                    #pragma unroll
                    for (int pp = 0; pp < 6; ++pp)
                        acc[pp] = fmaf(wj, v[pp + c], acc[pp]);
                }
            }
        }

        __syncthreads();   // previous chunk's sampling reads of cv complete
        if (act) {
            #pragma unroll
            for (int pp = 0; pp < 6; ++pp) cv[wv][pp][l] = acc[pp];
        }
        __syncthreads();   // cv visible to all waves

        // ---- sampling: wave wv owns positions base+wv and base+wv+3 ----
        #pragma unroll
        for (int rep = 0; rep < 2; ++rep) {
            const int pp  = wv + 3 * rep;
            const int pos = base + pp;

            const float offy = cv[0][pp][ls];
            const float offx = cv[1][pp][ls];
            const float mval = cv[2][pp][ls];
            const float mk = 1.0f / (1.0f + __expf(-mval));

            const float fy = (float)(h + kr - 3) + offy;
            const float fx = (float)(pos + kc - 3) + offx;
            const float fly = floorf(fy), flx = floorf(fx);
            const int iy0 = (int)fly, ix0 = (int)flx;
            const int iy1 = iy0 + 1,  ix1 = ix0 + 1;
            const float wy1 = fy - fly, wy0 = 1.0f - wy1;
            const float wx1 = fx - flx, wx0 = 1.0f - wx1;

            const float vy0 = (iy0 >= 0 && iy0 < HH) ? 1.0f : 0.0f;
            const float vy1 = (iy1 >= 0 && iy1 < HH) ? 1.0f : 0.0f;
            const float vx0 = (ix0 >= 0 && ix0 < WW) ? 1.0f : 0.0f;
            const float vx1 = (ix1 >= 0 && ix1 < WW) ? 1.0f : 0.0f;

            const int cy0 = min(max(iy0, 0), HH - 1) * WW;
            const int cy1 = min(max(iy1, 0), HH - 1) * WW;
            const int cx0 = min(max(ix0, 0), WW - 1);
            const int cx1 = min(max(ix1, 0), WW - 1);

            const float w00 = wy0 * wx0 * vy0 * vx0;
            const float w01 = wy0 * wx1 * vy0 * vx1;
            const float w10 = wy1 * wx0 * vy1 * vx0;
            const float w11 = wy1 * wx1 * vy1 * vx1;

            const float2 g00 = y2b[cy0 + cx0];
            const float2 g01 = y2b[cy0 + cx1];
            const float2 g10 = y2b[cy1 + cx0];
            const float2 g11 = y2b[cy1 + cx1];

            const float v0 = g00.x * w00 + g01.x * w01 + g10.x * w10 + g11.x * w11;
            const float v1 = g00.y * w00 + g01.y * w01 + g10.y * w10 + g11.y * w11;

            float tval = mk * fmaf(v0, wd0, v1 * wd1);
            tval = act ? tval : 0.0f;

            // wave-wide sum over taps (lanes 49..63 carry zero)
            float ssum = tval;
            #pragma unroll
            for (int off = 1; off < 64; off <<= 1)
                ssum += __shfl_xor(ssum, off);

            if (l == 0 && pos < 128) {
                const float o = ssum * bscale + gB;
                gate_row[pos] = 1.0f / (1.0f + __expf(-o));
            }
        }
    }

    __syncthreads();

    // ---- broadcast write: gate_row -> all 256 channels ----
    const size_t ob = (size_t)b * CC * HW + (size_t)h * WW;
    const float4* gr = (const float4*)gate_row;
    for (int idx = t; idx < CC * 32; idx += 192) {
        const int c  = idx >> 5;
        const int wq = idx & 31;
        ((float4*)(out + ob + (size_t)c * HW))[wq] = gr[wq];
    }
}

extern "C" void kernel_launch(void* const* d_in, const int* in_sizes, int n_in,
                              void* d_out, int out_size, void* d_ws, size_t ws_size,
                              hipStream_t stream) {
    const float* x        = (const float*)d_in[0];
    const float* w_off    = (const float*)d_in[1];
    const float* b_off    = (const float*)d_in[2];
    const float* w_dcn    = (const float*)d_in[3];
    const float* b_dcn    = (const float*)d_in[4];
    const float* bn_gamma = (const float*)d_in[5];
    const float* bn_beta  = (const float*)d_in[6];
    const float* bn_mean  = (const float*)d_in[7];
    const float* bn_var   = (const float*)d_in[8];
    float* out = (float*)d_out;

    float* y2 = (float*)d_ws;   // (B, H*W, 2) interleaved mean/max = 1 MiB

    reduce_meanmax<<<BB * HH, 512, 0, stream>>>(x, y2);
    deform_att<<<BB * HH, 192, 0, stream>>>(y2, w_off, b_off, w_dcn, b_dcn,
                                            bn_gamma, bn_beta, bn_mean, bn_var,
                                            out);
}

// Round 4
// 664.546 us; speedup vs baseline: 1.2141x; 1.1872x over previous
//
#include <hip/hip_runtime.h>
#include <cstdint>

#define BB 8
#define CC 256
#define HH 128
#define WW 128
#define HW (HH * WW)

// ---------------------------------------------------------------------------
// Kernel A: per-position channel mean & max of x -> y2 (B, H*W, 2) float2
// interleaved {mean, max}. One block per (b, h) row; 512 threads =
// 16 channel-groups x 32 float4 lanes.
// ---------------------------------------------------------------------------
__global__ __launch_bounds__(512) void reduce_meanmax(const float* __restrict__ x,
                                                      float* __restrict__ y2) {
    const int bh = blockIdx.x;
    const int b  = bh >> 7;
    const int h  = bh & 127;
    const int t  = threadIdx.x;
    const int wq = t & 31;       // float4 column: w = wq*4
    const int cg = t >> 5;       // channel group 0..15 (16 channels each)

    const float* xb = x + ((size_t)(b * CC + cg * 16) * HH + h) * WW;

    float4 s = make_float4(0.f, 0.f, 0.f, 0.f);
    float4 m = make_float4(-INFINITY, -INFINITY, -INFINITY, -INFINITY);
    #pragma unroll 4
    for (int i = 0; i < 16; ++i) {
        float4 v = ((const float4*)(xb + (size_t)i * HW))[wq];
        s.x += v.x; s.y += v.y; s.z += v.z; s.w += v.w;
        m.x = fmaxf(m.x, v.x); m.y = fmaxf(m.y, v.y);
        m.z = fmaxf(m.z, v.z); m.w = fmaxf(m.w, v.w);
    }

    __shared__ float4 ls[16][32];
    __shared__ float4 lm[16][32];
    ls[cg][wq] = s;
    lm[cg][wq] = m;
    __syncthreads();

    if (t < 32) {
        float4 S = ls[0][t];
        float4 M = lm[0][t];
        #pragma unroll
        for (int g = 1; g < 16; ++g) {
            float4 a = ls[g][t];
            float4 c = lm[g][t];
            S.x += a.x; S.y += a.y; S.z += a.z; S.w += a.w;
            M.x = fmaxf(M.x, c.x); M.y = fmaxf(M.y, c.y);
            M.z = fmaxf(M.z, c.z); M.w = fmaxf(M.w, c.w);
        }
        const float inv = 1.0f / 256.0f;
        float4 o0 = make_float4(S.x * inv, M.x, S.y * inv, M.y);
        float4 o1 = make_float4(S.z * inv, M.z, S.w * inv, M.w);
        float4* yo = (float4*)(y2 + ((size_t)b * HW + (size_t)h * WW) * 2);
        yo[2 * t]     = o0;
        yo[2 * t + 1] = o1;
    }
}

// round-to-nearest-even f32 -> bf16 (returned in low 16 bits)
__device__ __forceinline__ uint32_t f2bf(float f) {
    uint32_t u = __float_as_uint(f);
    return (u + 0x7FFFu + ((u >> 16) & 1u)) >> 16;
}

// ---------------------------------------------------------------------------
// Kernel B: channel-per-lane conv + deformable sampling + gate broadcast.
// Block = 192 threads (3 waves): wave 0 = dy channels, wave 1 = dx,
// wave 2 = mask; lane l < 49 = tap k. Weights held as 49 bf16x2 VGPRs
// (pair = same tap across the 2 input planes), loaded/packed ONCE.
// Positions processed in 8 chunks of 16; ILP-16 accumulators.
// ---------------------------------------------------------------------------
__global__ __launch_bounds__(192, 2) void deform_att(
    const float* __restrict__ y2,
    const float* __restrict__ w_off, const float* __restrict__ b_off,
    const float* __restrict__ w_dcn, const float* __restrict__ b_dcn,
    const float* __restrict__ bn_gamma, const float* __restrict__ bn_beta,
    const float* __restrict__ bn_mean, const float* __restrict__ bn_var,
    float* __restrict__ out)
{
    const int bh = blockIdx.x;
    const int b  = bh >> 7;
    const int h  = bh & 127;
    const int t  = threadIdx.x;
    const int wv = t >> 6;          // 0: dy, 1: dx, 2: mask
    const int l  = t & 63;
    const bool act = (l < 49);
    const int ls = act ? l : 0;     // clamped tap index

    __shared__ float patch[2][7][136];   // zero-padded row window, x+3 in [0,134)
    __shared__ float cv[3][16][52];      // conv outputs: [type][pos-in-chunk][tap]
    __shared__ float gate_row[128];

    const float2* y2b = (const float2*)y2 + (size_t)b * HW;

    // ---- stage the zero-padded 2x7x134 patch window into LDS ----
    for (int i = t; i < 7 * 136; i += 192) {
        const int r  = i / 136;
        const int xi = i % 136;
        const int xx = xi - 3;
        const int yy = h + r - 3;
        float2 v = make_float2(0.f, 0.f);
        if (yy >= 0 && yy < HH && xx >= 0 && xx < WW)
            v = y2b[yy * WW + xx];
        patch[0][r][xi] = v.x;
        patch[1][r][xi] = v.y;
    }

    // ---- per-lane channel weights: 49 bf16x2 regs, loaded once ----
    const int ch = (wv == 0) ? 2 * ls : (wv == 1) ? (2 * ls + 1) : (98 + ls);
    uint32_t wpk[49];
    {
        const float* wp = w_off + (size_t)ch * 98;
        #pragma unroll
        for (int k = 0; k < 49; ++k) {
            // lo = plane-0 (mean) weight at tap k, hi = plane-1 (max)
            wpk[k] = f2bf(wp[k]) | (f2bf(wp[49 + k]) << 16);
        }
    }
    const float b_reg = b_off[ch];
    const float wd0 = w_dcn[ls];
    const float wd1 = w_dcn[49 + ls];
    const int kr = ls / 7;
    const int kc = ls % 7;
    const float bscale = bn_gamma[0] * rsqrtf(bn_var[0] + 1e-5f);
    const float gB = (b_dcn[0] - bn_mean[0]) * bscale + bn_beta[0];

    __syncthreads();

    #pragma unroll 1
    for (int chunk = 0; chunk < 8; ++chunk) {
        const int base = chunk * 16;

        // ---- conv: this lane's channel for 16 positions ----
        float acc[16];
        #pragma unroll
        for (int pp = 0; pp < 16; ++pp) acc[pp] = b_reg;

        #pragma unroll
        for (int r = 0; r < 7; ++r) {
            float v0[22], v1[22];
            #pragma unroll
            for (int q = 0; q < 11; ++q) {
                float2 a = *(const float2*)&patch[0][r][base + 2 * q];
                float2 bb = *(const float2*)&patch[1][r][base + 2 * q];
                v0[2 * q] = a.x;  v0[2 * q + 1] = a.y;
                v1[2 * q] = bb.x; v1[2 * q + 1] = bb.y;
            }
            #pragma unroll
            for (int c = 0; c < 7; ++c) {
                const uint32_t pk = wpk[r * 7 + c];
                const float w0 = __uint_as_float(pk << 16);
                const float w1 = __uint_as_float(pk & 0xFFFF0000u);
                #pragma unroll
                for (int pp = 0; pp < 16; ++pp) {
                    acc[pp] = fmaf(w0, v0[pp + c], acc[pp]);
                    acc[pp] = fmaf(w1, v1[pp + c], acc[pp]);
                }
            }
        }

        __syncthreads();   // previous chunk's sampling reads of cv complete
        if (act) {
            #pragma unroll
            for (int pp = 0; pp < 16; ++pp) cv[wv][pp][l] = acc[pp];
        }
        __syncthreads();   // cv visible to all waves

        // ---- sampling: wave wv handles positions pp = wv, wv+3, ... ----
        #pragma unroll 1
        for (int pp = wv; pp < 16; pp += 3) {
            const int pos = base + pp;

            const float offy = cv[0][pp][ls];
            const float offx = cv[1][pp][ls];
            const float mval = cv[2][pp][ls];
            const float mk = 1.0f / (1.0f + __expf(-mval));

            const float fy = (float)(h + kr - 3) + offy;
            const float fx = (float)(pos + kc - 3) + offx;
            const float fly = floorf(fy), flx = floorf(fx);
            const int iy0 = (int)fly, ix0 = (int)flx;
            const int iy1 = iy0 + 1,  ix1 = ix0 + 1;
            const float wy1 = fy - fly, wy0 = 1.0f - wy1;
            const float wx1 = fx - flx, wx0 = 1.0f - wx1;

            const float vy0 = (iy0 >= 0 && iy0 < HH) ? 1.0f : 0.0f;
            const float vy1 = (iy1 >= 0 && iy1 < HH) ? 1.0f : 0.0f;
            const float vx0 = (ix0 >= 0 && ix0 < WW) ? 1.0f : 0.0f;
            const float vx1 = (ix1 >= 0 && ix1 < WW) ? 1.0f : 0.0f;

            const int cy0 = min(max(iy0, 0), HH - 1) * WW;
            const int cy1 = min(max(iy1, 0), HH - 1) * WW;
            const int cx0 = min(max(ix0, 0), WW - 1);
            const int cx1 = min(max(ix1, 0), WW - 1);

            const float w00 = wy0 * wx0 * vy0 * vx0;
            const float w01 = wy0 * wx1 * vy0 * vx1;
            const float w10 = wy1 * wx0 * vy1 * vx0;
            const float w11 = wy1 * wx1 * vy1 * vx1;

            const float2 g00 = y2b[cy0 + cx0];
            const float2 g01 = y2b[cy0 + cx1];
            const float2 g10 = y2b[cy1 + cx0];
            const float2 g11 = y2b[cy1 + cx1];

            const float v0s = g00.x * w00 + g01.x * w01 + g10.x * w10 + g11.x * w11;
            const float v1s = g00.y * w00 + g01.y * w01 + g10.y * w10 + g11.y * w11;

            float tval = mk * fmaf(v0s, wd0, v1s * wd1);
            tval = act ? tval : 0.0f;

            float ssum = tval;
            #pragma unroll
            for (int off = 1; off < 64; off <<= 1)
                ssum += __shfl_xor(ssum, off);

            if (l == 0) {
                const float o = ssum * bscale + gB;
                gate_row[pos] = 1.0f / (1.0f + __expf(-o));
            }
        }
    }

    __syncthreads();

    // ---- broadcast write: gate_row -> all 256 channels ----
    const size_t ob = (size_t)b * CC * HW + (size_t)h * WW;
    const float4* gr = (const float4*)gate_row;
    for (int idx = t; idx < CC * 32; idx += 192) {
        const int c  = idx >> 5;
        const int wq = idx & 31;
        ((float4*)(out + ob + (size_t)c * HW))[wq] = gr[wq];
    }
}

extern "C" void kernel_launch(void* const* d_in, const int* in_sizes, int n_in,
                              void* d_out, int out_size, void* d_ws, size_t ws_size,
                              hipStream_t stream) {
    const float* x        = (const float*)d_in[0];
    const float* w_off    = (const float*)d_in[1];
    const float* b_off    = (const float*)d_in[2];
    const float* w_dcn    = (const float*)d_in[3];
    const float* b_dcn    = (const float*)d_in[4];
    const float* bn_gamma = (const float*)d_in[5];
    const float* bn_beta  = (const float*)d_in[6];
    const float* bn_mean  = (const float*)d_in[7];
    const float* bn_var   = (const float*)d_in[8];
    float* out = (float*)d_out;

    float* y2 = (float*)d_ws;   // (B, H*W, 2) interleaved mean/max = 1 MiB

    reduce_meanmax<<<BB * HH, 512, 0, stream>>>(x, y2);
    deform_att<<<BB * HH, 192, 0, stream>>>(y2, w_off, b_off, w_dcn, b_dcn,
                                            bn_gamma, bn_beta, bn_mean, bn_var,
                                            out);
}

// Round 5
// 293.316 us; speedup vs baseline: 2.7506x; 2.2656x over previous
//
#include <hip/hip_runtime.h>
#include <cstdint>

#define BB 8
#define CC 256
#define HH 128
#define WW 128
#define HW (HH * WW)

// ---------------------------------------------------------------------------
// Kernel A: per-position channel mean & max of x -> y2 (B, H*W, 2) float2
// interleaved {mean, max}. One block per (b, h) row; 512 threads.
// ---------------------------------------------------------------------------
__global__ __launch_bounds__(512) void reduce_meanmax(const float* __restrict__ x,
                                                      float* __restrict__ y2) {
    const int bh = blockIdx.x;
    const int b  = bh >> 7;
    const int h  = bh & 127;
    const int t  = threadIdx.x;
    const int wq = t & 31;       // float4 column: w = wq*4
    const int cg = t >> 5;       // channel group 0..15 (16 channels each)

    const float* xb = x + ((size_t)(b * CC + cg * 16) * HH + h) * WW;

    float4 s = make_float4(0.f, 0.f, 0.f, 0.f);
    float4 m = make_float4(-INFINITY, -INFINITY, -INFINITY, -INFINITY);
    #pragma unroll 4
    for (int i = 0; i < 16; ++i) {
        float4 v = ((const float4*)(xb + (size_t)i * HW))[wq];
        s.x += v.x; s.y += v.y; s.z += v.z; s.w += v.w;
        m.x = fmaxf(m.x, v.x); m.y = fmaxf(m.y, v.y);
        m.z = fmaxf(m.z, v.z); m.w = fmaxf(m.w, v.w);
    }

    __shared__ float4 ls[16][32];
    __shared__ float4 lm[16][32];
    ls[cg][wq] = s;
    lm[cg][wq] = m;
    __syncthreads();

    if (t < 32) {
        float4 S = ls[0][t];
        float4 M = lm[0][t];
        #pragma unroll
        for (int g = 1; g < 16; ++g) {
            float4 a = ls[g][t];
            float4 c = lm[g][t];
            S.x += a.x; S.y += a.y; S.z += a.z; S.w += a.w;
            M.x = fmaxf(M.x, c.x); M.y = fmaxf(M.y, c.y);
            M.z = fmaxf(M.z, c.z); M.w = fmaxf(M.w, c.w);
        }
        const float inv = 1.0f / 256.0f;
        float4 o0 = make_float4(S.x * inv, M.x, S.y * inv, M.y);
        float4 o1 = make_float4(S.z * inv, M.z, S.w * inv, M.w);
        float4* yo = (float4*)(y2 + ((size_t)b * HW + (size_t)h * WW) * 2);
        yo[2 * t]     = o0;
        yo[2 * t + 1] = o1;
    }
}

// round-to-nearest-even f32 -> bf16 (low 16 bits)
__device__ __forceinline__ uint32_t f2bf(float f) {
    uint32_t u = __float_as_uint(f);
    return (u + 0x7FFFu + ((u >> 16) & 1u)) >> 16;
}

// ---------------------------------------------------------------------------
// Kernel B: channel-per-lane conv (weights in LDS, bf16x2-packed) +
// deformable sampling + gate broadcast.
// Block = 192 threads (3 waves): wave 0 = dy, wave 1 = dx, wave 2 = mask;
// lane l < 49 = tap. Weight LDS layout [type][tap][k] u32: lane stride
// 49 u32 (odd) -> conflict-free ds_read_b32.
// ---------------------------------------------------------------------------
__global__ __launch_bounds__(192) void deform_att(
    const float* __restrict__ y2,
    const float* __restrict__ w_off, const float* __restrict__ b_off,
    const float* __restrict__ w_dcn, const float* __restrict__ b_dcn,
    const float* __restrict__ bn_gamma, const float* __restrict__ bn_beta,
    const float* __restrict__ bn_mean, const float* __restrict__ bn_var,
    float* __restrict__ out)
{
    const int bh = blockIdx.x;
    const int b  = bh >> 7;
    const int h  = bh & 127;
    const int t  = threadIdx.x;
    const int wv = t >> 6;          // 0: dy, 1: dx, 2: mask
    const int l  = t & 63;
    const bool act = (l < 49);
    const int ls = act ? l : 0;     // clamped tap index

    __shared__ uint32_t wlds[3][49][49];  // [type][tap][k] packed bf16 {mean-w, max-w}
    __shared__ float patch[2][7][136];    // zero-padded row window
    __shared__ float cv[3][16][49];       // conv outputs [type][pos-in-chunk][tap]
    __shared__ float gate_row[128];

    const float2* y2b = (const float2*)y2 + (size_t)b * HW;

    // ---- stage packed weights into LDS (147 channels x 49 taps) ----
    for (int idx = t; idx < 147 * 49; idx += 192) {
        const int ch = idx / 49;         // source channel 0..146
        const int k  = idx % 49;
        const int ty  = (ch < 98) ? (ch & 1) : 2;
        const int tap = (ch < 98) ? (ch >> 1) : (ch - 98);
        const float* wp = w_off + (size_t)ch * 98;
        wlds[ty][tap][k] = f2bf(wp[k]) | (f2bf(wp[49 + k]) << 16);
    }

    // ---- stage the zero-padded 2x7x134 patch window into LDS ----
    for (int i = t; i < 7 * 136; i += 192) {
        const int r  = i / 136;
        const int xi = i % 136;
        const int xx = xi - 3;
        const int yy = h + r - 3;
        float2 v = make_float2(0.f, 0.f);
        if (yy >= 0 && yy < HH && xx >= 0 && xx < WW)
            v = y2b[yy * WW + xx];
        patch[0][r][xi] = v.x;
        patch[1][r][xi] = v.y;
    }

    const int ch = (wv == 0) ? 2 * ls : (wv == 1) ? (2 * ls + 1) : (98 + ls);
    const float b_reg = b_off[ch];
    const float wd0 = w_dcn[ls];
    const float wd1 = w_dcn[49 + ls];
    const int kr = ls / 7;
    const int kc = ls % 7;
    const float bscale = bn_gamma[0] * rsqrtf(bn_var[0] + 1e-5f);
    const float gB = (b_dcn[0] - bn_mean[0]) * bscale + bn_beta[0];

    __syncthreads();

    #pragma unroll 1
    for (int chunk = 0; chunk < 8; ++chunk) {
        const int base = chunk * 16;

        // ---- conv: this lane's channel for 16 positions ----
        float acc[16];
        #pragma unroll
        for (int pp = 0; pp < 16; ++pp) acc[pp] = b_reg;

        #pragma unroll
        for (int r = 0; r < 7; ++r) {
            float v0[22], v1[22];
            #pragma unroll
            for (int q = 0; q < 11; ++q) {
                float2 a  = *(const float2*)&patch[0][r][base + 2 * q];
                float2 bb = *(const float2*)&patch[1][r][base + 2 * q];
                v0[2 * q] = a.x;  v0[2 * q + 1] = a.y;
                v1[2 * q] = bb.x; v1[2 * q + 1] = bb.y;
            }
            #pragma unroll
            for (int c = 0; c < 7; ++c) {
                const uint32_t pk = wlds[wv][ls][r * 7 + c];
                const float w0 = __uint_as_float(pk << 16);
                const float w1 = __uint_as_float(pk & 0xFFFF0000u);
                #pragma unroll
                for (int pp = 0; pp < 16; ++pp) {
                    acc[pp] = fmaf(w0, v0[pp + c], acc[pp]);
                    acc[pp] = fmaf(w1, v1[pp + c], acc[pp]);
                }
            }
        }

        __syncthreads();   // previous chunk's sampling reads of cv complete
        if (act) {
            #pragma unroll
            for (int pp = 0; pp < 16; ++pp) cv[wv][pp][l] = acc[pp];
        }
        __syncthreads();   // cv visible to all waves

        // ---- sampling: wave wv handles positions pp = wv, wv+3, ... ----
        #pragma unroll 1
        for (int pp = wv; pp < 16; pp += 3) {
            const int pos = base + pp;

            const float offy = cv[0][pp][ls];
            const float offx = cv[1][pp][ls];
            const float mval = cv[2][pp][ls];
            const float mk = 1.0f / (1.0f + __expf(-mval));

            const float fy = (float)(h + kr - 3) + offy;
            const float fx = (float)(pos + kc - 3) + offx;
            const float fly = floorf(fy), flx = floorf(fx);
            const int iy0 = (int)fly, ix0 = (int)flx;
            const int iy1 = iy0 + 1,  ix1 = ix0 + 1;
            const float wy1 = fy - fly, wy0 = 1.0f - wy1;
            const float wx1 = fx - flx, wx0 = 1.0f - wx1;

            const float vy0 = (iy0 >= 0 && iy0 < HH) ? 1.0f : 0.0f;
            const float vy1 = (iy1 >= 0 && iy1 < HH) ? 1.0f : 0.0f;
            const float vx0 = (ix0 >= 0 && ix0 < WW) ? 1.0f : 0.0f;
            const float vx1 = (ix1 >= 0 && ix1 < WW) ? 1.0f : 0.0f;

            const int cy0 = min(max(iy0, 0), HH - 1) * WW;
            const int cy1 = min(max(iy1, 0), HH - 1) * WW;
            const int cx0 = min(max(ix0, 0), WW - 1);
            const int cx1 = min(max(ix1, 0), WW - 1);

            const float w00 = wy0 * wx0 * vy0 * vx0;
            const float w01 = wy0 * wx1 * vy0 * vx1;
            const float w10 = wy1 * wx0 * vy1 * vx0;
            const float w11 = wy1 * wx1 * vy1 * vx1;

            const float2 g00 = y2b[cy0 + cx0];
            const float2 g01 = y2b[cy0 + cx1];
            const float2 g10 = y2b[cy1 + cx0];
            const float2 g11 = y2b[cy1 + cx1];

            const float v0s = g00.x * w00 + g01.x * w01 + g10.x * w10 + g11.x * w11;
            const float v1s = g00.y * w00 + g01.y * w01 + g10.y * w10 + g11.y * w11;

            float tval = mk * fmaf(v0s, wd0, v1s * wd1);
            tval = act ? tval : 0.0f;

            float ssum = tval;
            #pragma unroll
            for (int off = 1; off < 64; off <<= 1)
                ssum += __shfl_xor(ssum, off);

            if (l == 0) {
                const float o = ssum * bscale + gB;
                gate_row[pos] = 1.0f / (1.0f + __expf(-o));
            }
        }
    }

    __syncthreads();

    // ---- broadcast write: gate_row -> all 256 channels ----
    const size_t ob = (size_t)b * CC * HW + (size_t)h * WW;
    const float4* gr = (const float4*)gate_row;
    for (int idx = t; idx < CC * 32; idx += 192) {
        const int c  = idx >> 5;
        const int wq = idx & 31;
        ((float4*)(out + ob + (size_t)c * HW))[wq] = gr[wq];
    }
}

extern "C" void kernel_launch(void* const* d_in, const int* in_sizes, int n_in,
                              void* d_out, int out_size, void* d_ws, size_t ws_size,
                              hipStream_t stream) {
    const float* x        = (const float*)d_in[0];
    const float* w_off    = (const float*)d_in[1];
    const float* b_off    = (const float*)d_in[2];
    const float* w_dcn    = (const float*)d_in[3];
    const float* b_dcn    = (const float*)d_in[4];
    const float* bn_gamma = (const float*)d_in[5];
    const float* bn_beta  = (const float*)d_in[6];
    const float* bn_mean  = (const float*)d_in[7];
    const float* bn_var   = (const float*)d_in[8];
    float* out = (float*)d_out;

    float* y2 = (float*)d_ws;   // (B, H*W, 2) interleaved mean/max = 1 MiB

    reduce_meanmax<<<BB * HH, 512, 0, stream>>>(x, y2);
    deform_att<<<BB * HH, 192, 0, stream>>>(y2, w_off, b_off, w_dcn, b_dcn,
                                            bn_gamma, bn_beta, bn_mean, bn_var,
                                            out);
}